// Round 2
// baseline (187.836 us; speedup 1.0000x reference)
//
#include <hip/hip_runtime.h>

// Problem: B=64, H=W=512 fp32. out = x + (f - conv3x3(x,k_b)) / 6, zero pad,
// cross-correlation (no kernel flip).
//
// R6 = R5 with the nontemporal-store compile error fixed (native ext_vector
// type instead of HIP_vector_type). Design unchanged:
//  - Full-row waves: lane l owns 8 contiguous floats; 64 lanes x 8 = 512 = one
//    full row. Row halos are exactly 2 shfls per row; image-edge halos are
//    compile-time zeros -> no single-active-lane fallback loads.
//  - 4 output rows per thread: 6 x-row loads per 4 outputs (1.5/row vs 3/row),
//    all loads issued straight-line -> deep MLP per wave; 8192 waves.
//  - Non-temporal stores for out (never re-read): keep out's 67 MB out of L3
//    so x+f (134 MB) can stay fully resident across iterations.
#define BB 64
#define HH 512
#define WW 512
#define RPT 4                         // output rows per thread
#define ROWS_PER_BLOCK (4 * RPT)      // 4 waves/block * RPT rows = 16
#define NBLOCKS (BB * HH / ROWS_PER_BLOCK)  // 2048

typedef float f32x4 __attribute__((ext_vector_type(4)));  // nt-store-legal

struct Row { float4 v0, v1; float l, r; };  // 8 floats + left/right halo

// cross-correlation row accumulate: weights (w0,w1,w2) multiply cols j-1,j,j+1
__device__ __forceinline__ void accum(float4& q0, float4& q1, const Row& w,
                                      float w0, float w1, float w2) {
    q0.x += w0 * w.l    + w1 * w.v0.x + w2 * w.v0.y;
    q0.y += w0 * w.v0.x + w1 * w.v0.y + w2 * w.v0.z;
    q0.z += w0 * w.v0.y + w1 * w.v0.z + w2 * w.v0.w;
    q0.w += w0 * w.v0.z + w1 * w.v0.w + w2 * w.v1.x;
    q1.x += w0 * w.v0.w + w1 * w.v1.x + w2 * w.v1.y;
    q1.y += w0 * w.v1.x + w1 * w.v1.y + w2 * w.v1.z;
    q1.z += w0 * w.v1.y + w1 * w.v1.z + w2 * w.v1.w;
    q1.w += w0 * w.v1.z + w1 * w.v1.w + w2 * w.r;
}

__global__ __launch_bounds__(256) void jacobi_v6_kernel(
    const float* __restrict__ x,
    const float* __restrict__ f,
    const float* __restrict__ k,
    float* __restrict__ out)
{
    const int tid  = threadIdx.x;
    const int lane = tid & 63;
    const int wv   = tid >> 6;

    // 32 row-blocks per image -> b scalar (SGPR) by construction.
    const int b  = blockIdx.x >> 5;
    const int rb = blockIdx.x & 31;
    const int r0 = (rb << 4) + wv * RPT;   // first output row of this wave

    const size_t img = (size_t)b * (HH * WW);
    const float* xb = x + img;
    const float* fb = f + img;
    float*       ob = out + img;

    const float* kb = k + b * 9;           // scalar -> s_load
    const float k00 = kb[0], k01 = kb[1], k02 = kb[2];
    const float k10 = kb[3], k11 = kb[4], k12 = kb[5];
    const float k20 = kb[6], k21 = kb[7], k22 = kb[8];

    const int col = lane << 3;             // first column owned by this lane

    // Load the RPT+2 stencil rows (r0-1 .. r0+RPT). r0 is wave-uniform, so
    // the image-edge branches are non-divergent; out-of-image rows are zeros.
    Row rows[RPT + 2];
    #pragma unroll
    for (int t = 0; t < RPT + 2; ++t) {
        const int rr = r0 - 1 + t;
        if (rr >= 0 && rr < HH) {
            const float* p = xb + (size_t)rr * WW + col;
            rows[t].v0 = *(const float4*)p;
            rows[t].v1 = *(const float4*)(p + 4);
        } else {
            rows[t].v0 = make_float4(0.f, 0.f, 0.f, 0.f);
            rows[t].v1 = make_float4(0.f, 0.f, 0.f, 0.f);
        }
    }

    // Halos: col-1 comes from lane l-1's last float, col+8 from lane l+1's
    // first float. Image edges (lane 0 left / lane 63 right) are zero pad.
    #pragma unroll
    for (int t = 0; t < RPT + 2; ++t) {
        const float lh = __shfl_up(rows[t].v1.w, 1);
        const float rh = __shfl_down(rows[t].v0.x, 1);
        rows[t].l = (lane == 0)  ? 0.f : lh;
        rows[t].r = (lane == 63) ? 0.f : rh;
    }

    const float inv6 = 1.f / 6.f;
    #pragma unroll
    for (int r = 0; r < RPT; ++r) {
        const size_t off = (size_t)(r0 + r) * WW + col;
        const float4 f0 = *(const float4*)(fb + off);
        const float4 f1 = *(const float4*)(fb + off + 4);

        float4 q0 = make_float4(0.f, 0.f, 0.f, 0.f);
        float4 q1 = make_float4(0.f, 0.f, 0.f, 0.f);
        accum(q0, q1, rows[r],     k00, k01, k02);   // stencil row i-1
        accum(q0, q1, rows[r + 1], k10, k11, k12);   // stencil row i
        accum(q0, q1, rows[r + 2], k20, k21, k22);   // stencil row i+1

        const Row& c = rows[r + 1];
        f32x4 o0, o1;
        o0.x = c.v0.x + (f0.x - q0.x) * inv6;
        o0.y = c.v0.y + (f0.y - q0.y) * inv6;
        o0.z = c.v0.z + (f0.z - q0.z) * inv6;
        o0.w = c.v0.w + (f0.w - q0.w) * inv6;
        o1.x = c.v1.x + (f1.x - q1.x) * inv6;
        o1.y = c.v1.y + (f1.y - q1.y) * inv6;
        o1.z = c.v1.z + (f1.z - q1.z) * inv6;
        o1.w = c.v1.w + (f1.w - q1.w) * inv6;

        // out is never re-read: non-temporal to keep it out of L3 so x+f stay
        // resident across iterations.
        __builtin_nontemporal_store(o0, (f32x4*)(ob + off));
        __builtin_nontemporal_store(o1, (f32x4*)(ob + off + 4));
    }
}

extern "C" void kernel_launch(void* const* d_in, const int* in_sizes, int n_in,
                              void* d_out, int out_size, void* d_ws, size_t ws_size,
                              hipStream_t stream) {
    const float* x  = (const float*)d_in[0];
    const float* f  = (const float*)d_in[1];
    const float* kk = (const float*)d_in[2];
    float* out = (float*)d_out;

    jacobi_v6_kernel<<<NBLOCKS, 256, 0, stream>>>(x, f, kk, out);
}

// Round 3
// 174.767 us; speedup vs baseline: 1.0748x; 1.0748x over previous
//
#include <hip/hip_runtime.h>

// Problem: B=64, H=W=512 fp32. out = x + (f - conv3x3(x,k_b)) / 6, zero pad,
// cross-correlation (no kernel flip).
//
// R7 (post-mortem of R6): keep the full-row-wave mapping (it cut FETCH_SIZE
// 98->77 MB as designed), revert the two regressions:
//  - DROP nontemporal stores. R6's WRITE_SIZE inflated 65.5->94.9 MB: the two
//    16B-per-lane stores are stride-32 interleaved wave-wide, so with L2/L3
//    bypassed each half-line became a partial HBM burst (~1.45x write
//    amplification). Write-back stores coalesce the halves in L2.
//  - RPT 4->2. R6's VGPR_Count=48 < the 60 floats of rows[6]: the compiler
//    sank the row loads into the compute to cut live ranges, serializing the
//    load->shfl->FMA chain (VALUBusy 16->6.7%). rows[4]=40 floats fits without
//    forcing that, and 4096 blocks = 2x oversubscription hides drain
//    (R6 occupancy 40%: 2048 blocks filled the machine exactly once).
#define BB 64
#define HH 512
#define WW 512
#define RPT 2                         // output rows per thread
#define ROWS_PER_BLOCK (4 * RPT)      // 4 waves/block * RPT rows = 8
#define NBLOCKS (BB * HH / ROWS_PER_BLOCK)  // 4096

struct Row { float4 v0, v1; float l, r; };  // 8 floats + left/right halo

// cross-correlation row accumulate: weights (w0,w1,w2) multiply cols j-1,j,j+1
__device__ __forceinline__ void accum(float4& q0, float4& q1, const Row& w,
                                      float w0, float w1, float w2) {
    q0.x += w0 * w.l    + w1 * w.v0.x + w2 * w.v0.y;
    q0.y += w0 * w.v0.x + w1 * w.v0.y + w2 * w.v0.z;
    q0.z += w0 * w.v0.y + w1 * w.v0.z + w2 * w.v0.w;
    q0.w += w0 * w.v0.z + w1 * w.v0.w + w2 * w.v1.x;
    q1.x += w0 * w.v0.w + w1 * w.v1.x + w2 * w.v1.y;
    q1.y += w0 * w.v1.x + w1 * w.v1.y + w2 * w.v1.z;
    q1.z += w0 * w.v1.y + w1 * w.v1.z + w2 * w.v1.w;
    q1.w += w0 * w.v1.z + w1 * w.v1.w + w2 * w.r;
}

__global__ __launch_bounds__(256) void jacobi_v7_kernel(
    const float* __restrict__ x,
    const float* __restrict__ f,
    const float* __restrict__ k,
    float* __restrict__ out)
{
    const int tid  = threadIdx.x;
    const int lane = tid & 63;
    const int wv   = tid >> 6;

    // 64 row-blocks per image -> b scalar (SGPR) by construction.
    const int b  = blockIdx.x >> 6;
    const int rb = blockIdx.x & 63;
    const int r0 = (rb << 3) + wv * RPT;   // first output row of this wave

    const size_t img = (size_t)b * (HH * WW);
    const float* xb = x + img;
    const float* fb = f + img;
    float*       ob = out + img;

    const float* kb = k + b * 9;           // scalar -> s_load
    const float k00 = kb[0], k01 = kb[1], k02 = kb[2];
    const float k10 = kb[3], k11 = kb[4], k12 = kb[5];
    const float k20 = kb[6], k21 = kb[7], k22 = kb[8];

    const int col = lane << 3;             // first column owned by this lane

    // Load the RPT+2 stencil rows (r0-1 .. r0+RPT). r0 is wave-uniform, so
    // the image-edge branches are non-divergent; out-of-image rows are zeros.
    Row rows[RPT + 2];
    #pragma unroll
    for (int t = 0; t < RPT + 2; ++t) {
        const int rr = r0 - 1 + t;
        if (rr >= 0 && rr < HH) {
            const float* p = xb + (size_t)rr * WW + col;
            rows[t].v0 = *(const float4*)p;
            rows[t].v1 = *(const float4*)(p + 4);
        } else {
            rows[t].v0 = make_float4(0.f, 0.f, 0.f, 0.f);
            rows[t].v1 = make_float4(0.f, 0.f, 0.f, 0.f);
        }
    }

    // Halos: col-1 comes from lane l-1's last float, col+8 from lane l+1's
    // first float. Image edges (lane 0 left / lane 63 right) are zero pad.
    #pragma unroll
    for (int t = 0; t < RPT + 2; ++t) {
        const float lh = __shfl_up(rows[t].v1.w, 1);
        const float rh = __shfl_down(rows[t].v0.x, 1);
        rows[t].l = (lane == 0)  ? 0.f : lh;
        rows[t].r = (lane == 63) ? 0.f : rh;
    }

    const float inv6 = 1.f / 6.f;
    #pragma unroll
    for (int r = 0; r < RPT; ++r) {
        const size_t off = (size_t)(r0 + r) * WW + col;
        const float4 f0 = *(const float4*)(fb + off);
        const float4 f1 = *(const float4*)(fb + off + 4);

        float4 q0 = make_float4(0.f, 0.f, 0.f, 0.f);
        float4 q1 = make_float4(0.f, 0.f, 0.f, 0.f);
        accum(q0, q1, rows[r],     k00, k01, k02);   // stencil row i-1
        accum(q0, q1, rows[r + 1], k10, k11, k12);   // stencil row i
        accum(q0, q1, rows[r + 2], k20, k21, k22);   // stencil row i+1

        const Row& c = rows[r + 1];
        float4 o0, o1;
        o0.x = c.v0.x + (f0.x - q0.x) * inv6;
        o0.y = c.v0.y + (f0.y - q0.y) * inv6;
        o0.z = c.v0.z + (f0.z - q0.z) * inv6;
        o0.w = c.v0.w + (f0.w - q0.w) * inv6;
        o1.x = c.v1.x + (f1.x - q1.x) * inv6;
        o1.y = c.v1.y + (f1.y - q1.y) * inv6;
        o1.z = c.v1.z + (f1.z - q1.z) * inv6;
        o1.w = c.v1.w + (f1.w - q1.w) * inv6;

        *(float4*)(ob + off)     = o0;   // write-back: halves coalesce in L2
        *(float4*)(ob + off + 4) = o1;
    }
}

extern "C" void kernel_launch(void* const* d_in, const int* in_sizes, int n_in,
                              void* d_out, int out_size, void* d_ws, size_t ws_size,
                              hipStream_t stream) {
    const float* x  = (const float*)d_in[0];
    const float* f  = (const float*)d_in[1];
    const float* kk = (const float*)d_in[2];
    float* out = (float*)d_out;

    jacobi_v7_kernel<<<NBLOCKS, 256, 0, stream>>>(x, f, kk, out);
}

// Round 4
// 170.471 us; speedup vs baseline: 1.1019x; 1.0252x over previous
//
#include <hip/hip_runtime.h>

// Problem: B=64, H=W=512 fp32. out = x + (f - conv3x3(x,k_b)) / 6, zero pad,
// cross-correlation (no kernel flip).
//
// R8 (post-mortem of R7): both R4 and R7 were latency-bound on compiler-
// serialized load chains (VGPR=20/32 => loads sunk into uses => ~6 serial
// round trips => ~5us wave lifetimes), and R7's interleaved per-lane dual
// store inflated WRITE_SIZE 1.25x (each store instr covered half of every
// 64B line, strided).
//  - Split-quad ownership: lane l owns quads at col 4l AND col 256+4l (half a
//    row apart). Every load AND store instruction has a perfectly contiguous
//    1024B wave footprint (fixes write amplification), and ALL halos come
//    from shfls: qA.r@lane63 = lane0's qB.x, qB.l@lane0 = lane63's qA.w,
//    image edges are compile-time zeros. Zero masked edge loads.
//  - sched_barrier(0) fence between the load block (12 dwordx4: 4 x-rows +
//    2 f-rows, 2 quads each) and shfl/compute/store: compiler cannot sink
//    loads across it, so they issue back-to-back -> one overlapped latency
//    round trip instead of ~6 serial ones.
#define BB 64
#define HH 512
#define WW 512
#define RPT 2                         // output rows per thread
#define ROWS_PER_BLOCK (4 * RPT)      // 4 waves/block * RPT rows = 8
#define NBLOCKS (BB * HH / ROWS_PER_BLOCK)  // 4096

struct Q { float4 v; float l, r; };   // quad + left/right halo floats

// cross-correlation accumulate: (w0,w1,w2) multiply cols j-1,j,j+1
__device__ __forceinline__ void accumq(float4& q, const Q& w,
                                       float w0, float w1, float w2) {
    q.x += w0 * w.l   + w1 * w.v.x + w2 * w.v.y;
    q.y += w0 * w.v.x + w1 * w.v.y + w2 * w.v.z;
    q.z += w0 * w.v.y + w1 * w.v.z + w2 * w.v.w;
    q.w += w0 * w.v.z + w1 * w.v.w + w2 * w.r;
}

__global__ __launch_bounds__(256) void jacobi_v8_kernel(
    const float* __restrict__ x,
    const float* __restrict__ f,
    const float* __restrict__ k,
    float* __restrict__ out)
{
    const int tid  = threadIdx.x;
    const int lane = tid & 63;
    const int wv   = tid >> 6;

    // 64 row-blocks per image -> b scalar (SGPR) by construction.
    const int b  = blockIdx.x >> 6;
    const int rb = blockIdx.x & 63;
    const int r0 = (rb << 3) + wv * RPT;   // first output row of this wave

    const size_t img = (size_t)b * (HH * WW);
    const float* xb = x + img;
    const float* fb = f + img;
    float*       ob = out + img;

    const float* kb = k + b * 9;           // scalar -> s_load
    const float k00 = kb[0], k01 = kb[1], k02 = kb[2];
    const float k10 = kb[3], k11 = kb[4], k12 = kb[5];
    const float k20 = kb[6], k21 = kb[7], k22 = kb[8];

    const int col = lane << 2;             // quad A column; quad B = col+256

    // ---- load block: all VMEM issued back-to-back, pinned above the fence
    float4 xa[RPT + 2], xq[RPT + 2];       // x rows r0-1 .. r0+RPT, two quads
    #pragma unroll
    for (int t = 0; t < RPT + 2; ++t) {
        const int rr = r0 - 1 + t;         // wave-uniform branch
        if (rr >= 0 && rr < HH) {
            const float* p = xb + (size_t)rr * WW + col;
            xa[t] = *(const float4*)p;
            xq[t] = *(const float4*)(p + 256);
        } else {
            xa[t] = make_float4(0.f, 0.f, 0.f, 0.f);
            xq[t] = make_float4(0.f, 0.f, 0.f, 0.f);
        }
    }
    float4 fa[RPT], fq[RPT];
    #pragma unroll
    for (int r = 0; r < RPT; ++r) {
        const float* p = fb + (size_t)(r0 + r) * WW + col;
        fa[r] = *(const float4*)p;
        fq[r] = *(const float4*)(p + 256);
    }
    __builtin_amdgcn_sched_barrier(0);     // loads stay above; no sinking

    // ---- halos: entirely via shfl, zero masked loads
    Q A[RPT + 2], B[RPT + 2];
    #pragma unroll
    for (int t = 0; t < RPT + 2; ++t) {
        const float a_l  = __shfl_up(xa[t].w, 1);
        const float a_r  = __shfl_down(xa[t].x, 1);
        const float b_l  = __shfl_up(xq[t].w, 1);
        const float b_r  = __shfl_down(xq[t].x, 1);
        const float aw63 = __shfl(xa[t].w, 63);   // float[255]
        const float bx0  = __shfl(xq[t].x, 0);    // float[256]
        A[t].v = xa[t];
        B[t].v = xq[t];
        A[t].l = (lane == 0)  ? 0.f  : a_l;       // image left edge pad
        A[t].r = (lane == 63) ? bx0  : a_r;       // col 256 from quad B
        B[t].l = (lane == 0)  ? aw63 : b_l;       // col 255 from quad A
        B[t].r = (lane == 63) ? 0.f  : b_r;       // image right edge pad
    }

    const float inv6 = 1.f / 6.f;
    #pragma unroll
    for (int r = 0; r < RPT; ++r) {
        float4 qa = make_float4(0.f, 0.f, 0.f, 0.f);
        float4 qb = make_float4(0.f, 0.f, 0.f, 0.f);
        accumq(qa, A[r],     k00, k01, k02);   // stencil row i-1
        accumq(qa, A[r + 1], k10, k11, k12);   // stencil row i
        accumq(qa, A[r + 2], k20, k21, k22);   // stencil row i+1
        accumq(qb, B[r],     k00, k01, k02);
        accumq(qb, B[r + 1], k10, k11, k12);
        accumq(qb, B[r + 2], k20, k21, k22);

        const float4 ca = A[r + 1].v;
        const float4 cb = B[r + 1].v;
        float4 oa, obq;
        oa.x  = ca.x + (fa[r].x - qa.x) * inv6;
        oa.y  = ca.y + (fa[r].y - qa.y) * inv6;
        oa.z  = ca.z + (fa[r].z - qa.z) * inv6;
        oa.w  = ca.w + (fa[r].w - qa.w) * inv6;
        obq.x = cb.x + (fq[r].x - qb.x) * inv6;
        obq.y = cb.y + (fq[r].y - qb.y) * inv6;
        obq.z = cb.z + (fq[r].z - qb.z) * inv6;
        obq.w = cb.w + (fq[r].w - qb.w) * inv6;

        float* po = ob + (size_t)(r0 + r) * WW + col;
        *(float4*)po         = oa;    // wave footprint: contiguous 1024 B
        *(float4*)(po + 256) = obq;   // wave footprint: contiguous 1024 B
    }
}

extern "C" void kernel_launch(void* const* d_in, const int* in_sizes, int n_in,
                              void* d_out, int out_size, void* d_ws, size_t ws_size,
                              hipStream_t stream) {
    const float* x  = (const float*)d_in[0];
    const float* f  = (const float*)d_in[1];
    const float* kk = (const float*)d_in[2];
    float* out = (float*)d_out;

    jacobi_v8_kernel<<<NBLOCKS, 256, 0, stream>>>(x, f, kk, out);
}

// Round 6
// 165.557 us; speedup vs baseline: 1.1346x; 1.0297x over previous
//
#include <hip/hip_runtime.h>

// Problem: B=64, H=W=512 fp32. out = x + (f - conv3x3(x,k_b)) / 6, zero pad,
// cross-correlation (no kernel flip).
//
// R9 (post-mortem of R8): this kernel is Little's-law bound — achieved BW =
// bytes-in-flight / latency, and bytes-in-flight scales with waves resident
// in their load window. R8's fat waves (16384) lost to R4's thin waves
// (65536) despite 25% less FETCH. So: back to one-ROW waves (32768), keeping
// R8's two proven wins:
//  - split-quad ownership (lane l owns quads at col 4l and 256+4l): every
//    load AND store instruction has a contiguous 1024B wave footprint
//    (WRITE_SIZE was exactly 65536 KB in R8), all halos via shfl, zero
//    single-lane edge loads.
//  - sched_barrier(0) fence: the 8-load block (3 x-rows + 1 f-row, 2 quads
//    each) issues back-to-back; compiler cannot sink loads into uses.
// New in R9: out-of-image stencil rows handled by CLAMPING the row address
// and ZEROING that row's kernel weights (wave-uniform scalar selects) ->
// every wave is straight-line, no branches around loads at all.
// (Resubmitted verbatim after an infra-only failure: "MI355X container
// failed twice" — kernel never ran.)
#define BB 64
#define HH 512
#define WW 512
#define NBLOCKS (BB * HH / 4)   // one row per wave, 4 waves/block -> 8192

struct Q { float4 v; float l, r; };   // quad + left/right halo floats

// cross-correlation accumulate: (w0,w1,w2) multiply cols j-1,j,j+1
__device__ __forceinline__ void accumq(float4& q, const Q& w,
                                       float w0, float w1, float w2) {
    q.x += w0 * w.l   + w1 * w.v.x + w2 * w.v.y;
    q.y += w0 * w.v.x + w1 * w.v.y + w2 * w.v.z;
    q.z += w0 * w.v.y + w1 * w.v.z + w2 * w.v.w;
    q.w += w0 * w.v.z + w1 * w.v.w + w2 * w.r;
}

__global__ __launch_bounds__(256) void jacobi_v9_kernel(
    const float* __restrict__ x,
    const float* __restrict__ f,
    const float* __restrict__ k,
    float* __restrict__ out)
{
    const int tid  = threadIdx.x;
    const int lane = tid & 63;
    const int wv   = tid >> 6;

    // 128 row-groups per image -> b scalar (SGPR) by construction.
    const int b  = blockIdx.x >> 7;
    const int rg = blockIdx.x & 127;
    const int i  = (rg << 2) + wv;         // this wave's output row

    // clamped stencil-row addresses; out-of-image rows get zero WEIGHTS below
    const int im = (i > 0)      ? i - 1 : 0;
    const int ip = (i < HH - 1) ? i + 1 : HH - 1;

    const size_t img = (size_t)b * (HH * WW);
    const float* xb = x + img;
    const float* fb = f + img;
    float*       ob = out + img;

    const float* kb = k + b * 9;           // scalar -> s_load
    const float k10 = kb[3], k11 = kb[4], k12 = kb[5];
    // row i-1 / i+1 weights, zeroed when that row is outside the image
    const float k00 = (i > 0)      ? kb[0] : 0.f;
    const float k01 = (i > 0)      ? kb[1] : 0.f;
    const float k02 = (i > 0)      ? kb[2] : 0.f;
    const float k20 = (i < HH - 1) ? kb[6] : 0.f;
    const float k21 = (i < HH - 1) ? kb[7] : 0.f;
    const float k22 = (i < HH - 1) ? kb[8] : 0.f;

    const int col = lane << 2;             // quad A column; quad B = col+256

    // ---- load block: 8 contiguous-footprint dwordx4, straight-line, fenced
    const float* pm = xb + (size_t)im * WW + col;
    const float* pc = xb + (size_t)i  * WW + col;
    const float* pp = xb + (size_t)ip * WW + col;
    const float* pf = fb + (size_t)i  * WW + col;
    float4 xma = *(const float4*)pm,  xmb = *(const float4*)(pm + 256);
    float4 xca = *(const float4*)pc,  xcb = *(const float4*)(pc + 256);
    float4 xpa = *(const float4*)pp,  xpb = *(const float4*)(pp + 256);
    float4 ffa = *(const float4*)pf,  ffb = *(const float4*)(pf + 256);
    __builtin_amdgcn_sched_barrier(0);     // loads stay above; no sinking

    // ---- halos: entirely via shfl, zero masked loads
    float4 xa[3] = { xma, xca, xpa };
    float4 xq[3] = { xmb, xcb, xpb };
    Q A[3], B[3];
    #pragma unroll
    for (int t = 0; t < 3; ++t) {
        const float a_l  = __shfl_up(xa[t].w, 1);
        const float a_r  = __shfl_down(xa[t].x, 1);
        const float b_l  = __shfl_up(xq[t].w, 1);
        const float b_r  = __shfl_down(xq[t].x, 1);
        const float aw63 = __shfl(xa[t].w, 63);   // float[255]
        const float bx0  = __shfl(xq[t].x, 0);    // float[256]
        A[t].v = xa[t];
        B[t].v = xq[t];
        A[t].l = (lane == 0)  ? 0.f  : a_l;       // image left edge pad
        A[t].r = (lane == 63) ? bx0  : a_r;       // col 256 from quad B
        B[t].l = (lane == 0)  ? aw63 : b_l;       // col 255 from quad A
        B[t].r = (lane == 63) ? 0.f  : b_r;       // image right edge pad
    }

    float4 qa = make_float4(0.f, 0.f, 0.f, 0.f);
    float4 qb = make_float4(0.f, 0.f, 0.f, 0.f);
    accumq(qa, A[0], k00, k01, k02);   // stencil row i-1 (weights 0 if padded)
    accumq(qa, A[1], k10, k11, k12);   // stencil row i
    accumq(qa, A[2], k20, k21, k22);   // stencil row i+1 (weights 0 if padded)
    accumq(qb, B[0], k00, k01, k02);
    accumq(qb, B[1], k10, k11, k12);
    accumq(qb, B[2], k20, k21, k22);

    const float inv6 = 1.f / 6.f;
    float4 oa, obq;
    oa.x  = xca.x + (ffa.x - qa.x) * inv6;
    oa.y  = xca.y + (ffa.y - qa.y) * inv6;
    oa.z  = xca.z + (ffa.z - qa.z) * inv6;
    oa.w  = xca.w + (ffa.w - qa.w) * inv6;
    obq.x = xcb.x + (ffb.x - qb.x) * inv6;
    obq.y = xcb.y + (ffb.y - qb.y) * inv6;
    obq.z = xcb.z + (ffb.z - qb.z) * inv6;
    obq.w = xcb.w + (ffb.w - qb.w) * inv6;

    float* po = ob + (size_t)i * WW + col;
    *(float4*)po         = oa;    // wave footprint: contiguous 1024 B
    *(float4*)(po + 256) = obq;   // wave footprint: contiguous 1024 B
}

extern "C" void kernel_launch(void* const* d_in, const int* in_sizes, int n_in,
                              void* d_out, int out_size, void* d_ws, size_t ws_size,
                              hipStream_t stream) {
    const float* x  = (const float*)d_in[0];
    const float* f  = (const float*)d_in[1];
    const float* kk = (const float*)d_in[2];
    float* out = (float*)d_out;

    jacobi_v9_kernel<<<NBLOCKS, 256, 0, stream>>>(x, f, kk, out);
}